// Round 6
// baseline (376.439 us; speedup 1.0000x reference)
//
#include <hip/hip_runtime.h>

#define NN 256
#define XD 256
#define ED 128

typedef __attribute__((ext_vector_type(8))) short short8;
typedef __attribute__((ext_vector_type(4))) float f32x4;

__device__ __forceinline__ unsigned short f2bf(float f) {
    unsigned u = __builtin_bit_cast(unsigned, f);
    u += 0x7FFF + ((u >> 16) & 1);
    return (unsigned short)(u >> 16);
}

#define MFMA16(a, b, c) __builtin_amdgcn_mfma_f32_16x16x32_bf16(a, b, c, 0, 0, 0)

// ---------------------------------------------------------------------------
// Weight prep: transpose + bf16-convert all 7 weights to [n][k] layout.
// ---------------------------------------------------------------------------
__global__ __launch_bounds__(256) void wprep_kernel(
    const float* __restrict__ Wq, const float* __restrict__ Wk,
    const float* __restrict__ Wv, const float* __restrict__ Wxo,
    const float* __restrict__ Wem, const float* __restrict__ Wea,
    const float* __restrict__ Weo,
    short* __restrict__ WqT, short* __restrict__ WkT,
    short* __restrict__ WvT, short* __restrict__ WxoT,
    short* __restrict__ WemT, short* __restrict__ WeaT,
    short* __restrict__ WeoT)
{
    __shared__ float sT[32][33];
    int blk = blockIdx.x;
    const float* src; short* dst; int din, dout, tile;
    if (blk < 256) {
        int m = blk >> 6; tile = blk & 63; din = 256; dout = 256;
        src = m == 0 ? Wq : (m == 1 ? Wk : (m == 2 ? Wv : Wxo));
        dst = m == 0 ? WqT : (m == 1 ? WkT : (m == 2 ? WvT : WxoT));
    } else if (blk < 320) {
        int m = (blk - 256) >> 5; tile = (blk - 256) & 31; din = 128; dout = 256;
        src = m == 0 ? Wem : Wea; dst = m == 0 ? WemT : WeaT;
    } else {
        tile = blk - 320; din = 256; dout = 128;
        src = Weo; dst = WeoT;
    }
    int ksh = (din == 256) ? 3 : 2;
    int kt = tile & ((1 << ksh) - 1);
    int nt = tile >> ksh;
    int c = threadIdx.x & 31, rbase = threadIdx.x >> 5;
    #pragma unroll
    for (int p = 0; p < 4; ++p) {
        int r = rbase + p * 8;
        sT[r][c] = src[(kt * 32 + r) * dout + nt * 32 + c];
    }
    __syncthreads();
    #pragma unroll
    for (int p = 0; p < 4; ++p) {
        int r = rbase + p * 8;
        dst[(nt * 32 + r) * din + kt * 32 + c] = (short)f2bf(sT[c][r]);
    }
}

// ---------------------------------------------------------------------------
// Q/K projection via MFMA. grid = 16 m-tiles (64 rows) x 2 mats = 32 blocks.
// Q row-major fp32 pre-scaled by 1/sqrt(32); K stored transposed KT[b][c][j].
// ---------------------------------------------------------------------------
__global__ __launch_bounds__(512) void proj_qk_kernel(
    const float* __restrict__ x, const short* __restrict__ WqT,
    const short* __restrict__ WkT, const float* __restrict__ bq,
    const float* __restrict__ bk, float* __restrict__ Qs,
    float* __restrict__ KT)
{
    __shared__ unsigned short sX[64 * 264];
    const int blk = blockIdx.x;
    const int mtile = blk >> 1;   // 0..15 (64-row tile of the 1024 rows)
    const int mat   = blk & 1;    // 0: Q, 1: K
    const int tid = threadIdx.x, wave = tid >> 6, lane = tid & 63;
    const int quad = lane >> 4, l16 = lane & 15;

    {   // stage x tile fp32 -> bf16
        const float4* src4 = (const float4*)(x + (size_t)mtile * 64 * XD);
        #pragma unroll
        for (int it = 0; it < 8; ++it) {
            int idx4 = tid + it * 512;
            float4 v = src4[idx4];
            int elem = idx4 * 4, row = elem >> 8, col = elem & 255;
            short4 p = make_short4((short)f2bf(v.x), (short)f2bf(v.y),
                                   (short)f2bf(v.z), (short)f2bf(v.w));
            *(short4*)&sX[row * 264 + col] = p;
        }
    }
    __syncthreads();

    const short* WT   = mat ? WkT : WqT;
    const float* bias = mat ? bk : bq;
    const int c0 = wave * 32;

    f32x4 acc[4][2] = {};
    for (int ks = 0; ks < 8; ++ks) {
        short8 bfrag[2];
        #pragma unroll
        for (int ct = 0; ct < 2; ++ct)
            bfrag[ct] = *(const short8*)&WT[(c0 + ct * 16 + l16) * 256 + ks * 32 + quad * 8];
        #pragma unroll
        for (int mt = 0; mt < 4; ++mt) {
            short8 a = *(const short8*)&sX[(mt * 16 + l16) * 264 + ks * 32 + quad * 8];
            acc[mt][0] = MFMA16(a, bfrag[0], acc[mt][0]);
            acc[mt][1] = MFMA16(a, bfrag[1], acc[mt][1]);
        }
    }

    if (mat == 0) {
        #pragma unroll
        for (int mt = 0; mt < 4; ++mt)
            #pragma unroll
            for (int ct = 0; ct < 2; ++ct) {
                int cc = c0 + ct * 16 + l16;
                float bb = bias[cc];
                #pragma unroll
                for (int r = 0; r < 4; ++r)
                    Qs[(size_t)(mtile * 64 + mt * 16 + quad * 4 + r) * 256 + cc] =
                        (acc[mt][ct][r] + bb) * 0.17677669529663687f;
            }
    } else {
        int b = mtile >> 2, j0p = (mtile & 3) * 64;
        #pragma unroll
        for (int mt = 0; mt < 4; ++mt)
            #pragma unroll
            for (int ct = 0; ct < 2; ++ct) {
                int cc = c0 + ct * 16 + l16;
                float bb = bias[cc];
                f32x4 st;
                #pragma unroll
                for (int r = 0; r < 4; ++r) st[r] = acc[mt][ct][r] + bb;
                *(f32x4*)&KT[(size_t)(b * 256 + cc) * 256 + j0p + mt * 16 + quad * 4] = st;
            }
    }
}

// ---------------------------------------------------------------------------
// V = x@Wv + bv (bf16 in LDS), then newX = V@Wxo + bxo.
// grid = 16 m-tiles (64 rows), 512 threads.
// ---------------------------------------------------------------------------
__global__ __launch_bounds__(512) void proj_vx_kernel(
    const float* __restrict__ x, const short* __restrict__ WvT,
    const float* __restrict__ bv, const short* __restrict__ WxoT,
    const float* __restrict__ bxo, float* __restrict__ outX)
{
    __shared__ unsigned short sX[64 * 264];
    __shared__ unsigned short sV[64 * 264];
    const int mtile = blockIdx.x;
    const int tid = threadIdx.x, wave = tid >> 6, lane = tid & 63;
    const int quad = lane >> 4, l16 = lane & 15;

    {
        const float4* src4 = (const float4*)(x + (size_t)mtile * 64 * XD);
        #pragma unroll
        for (int it = 0; it < 8; ++it) {
            int idx4 = tid + it * 512;
            float4 v = src4[idx4];
            int elem = idx4 * 4, row = elem >> 8, col = elem & 255;
            short4 p = make_short4((short)f2bf(v.x), (short)f2bf(v.y),
                                   (short)f2bf(v.z), (short)f2bf(v.w));
            *(short4*)&sX[row * 264 + col] = p;
        }
    }
    __syncthreads();

    const int c0 = wave * 32;
    f32x4 acc[4][2] = {};
    for (int ks = 0; ks < 8; ++ks) {
        short8 bfrag[2];
        #pragma unroll
        for (int ct = 0; ct < 2; ++ct)
            bfrag[ct] = *(const short8*)&WvT[(c0 + ct * 16 + l16) * 256 + ks * 32 + quad * 8];
        #pragma unroll
        for (int mt = 0; mt < 4; ++mt) {
            short8 a = *(const short8*)&sX[(mt * 16 + l16) * 264 + ks * 32 + quad * 8];
            acc[mt][0] = MFMA16(a, bfrag[0], acc[mt][0]);
            acc[mt][1] = MFMA16(a, bfrag[1], acc[mt][1]);
        }
    }
    #pragma unroll
    for (int mt = 0; mt < 4; ++mt)
        #pragma unroll
        for (int ct = 0; ct < 2; ++ct) {
            int cc = c0 + ct * 16 + l16;
            float bb = bv[cc];
            #pragma unroll
            for (int r = 0; r < 4; ++r)
                sV[(mt * 16 + quad * 4 + r) * 264 + cc] = f2bf(acc[mt][ct][r] + bb);
        }
    __syncthreads();

    f32x4 acc2[4][2] = {};
    for (int ks = 0; ks < 8; ++ks) {
        short8 bfrag[2];
        #pragma unroll
        for (int ct = 0; ct < 2; ++ct)
            bfrag[ct] = *(const short8*)&WxoT[(c0 + ct * 16 + l16) * 256 + ks * 32 + quad * 8];
        #pragma unroll
        for (int mt = 0; mt < 4; ++mt) {
            short8 a = *(const short8*)&sV[(mt * 16 + l16) * 264 + ks * 32 + quad * 8];
            acc2[mt][0] = MFMA16(a, bfrag[0], acc2[mt][0]);
            acc2[mt][1] = MFMA16(a, bfrag[1], acc2[mt][1]);
        }
    }
    #pragma unroll
    for (int mt = 0; mt < 4; ++mt)
        #pragma unroll
        for (int ct = 0; ct < 2; ++ct) {
            int cc = c0 + ct * 16 + l16;
            float bb = bxo[cc];
            #pragma unroll
            for (int r = 0; r < 4; ++r)
                outX[(size_t)(mtile * 64 + mt * 16 + quad * 4 + r) * 256 + cc] =
                    acc2[mt][ct][r] + bb;
        }
}

// ---------------------------------------------------------------------------
// Fused edge kernel v9: v3/v8 tile math re-partitioned to 8 waves (512 thr).
//   Wave w owns c-window w*32 in GEMM1 (ct-outer: live weights B1[4]+B2[4]
//   = 32 VGPR) and 16-o slice in GEMM2 (B3[8]). Per-block MFMA count, weight/
//   KT/e traffic, LDS layout (pitch 140/268, 0-conflict), 2 barriers: all
//   IDENTICAL to v3. Per-wave chain halves; 3 blocks/CU x 8 waves = 24
//   waves/CU (6/SIMD) vs v3's 12. setprio kept (v8: +2.5%).
// ---------------------------------------------------------------------------
__global__ __launch_bounds__(512, 6) void fused_edge_kernel(
    const float* __restrict__ e, const float* __restrict__ Qs,
    const float* __restrict__ KT, const short* __restrict__ WemT,
    const short* __restrict__ WeaT, const short* __restrict__ WeoT,
    const float* __restrict__ bem, const float* __restrict__ bea,
    const float* __restrict__ beo, float* __restrict__ outE)
{
    __shared__ unsigned short sE[64 * 140];   // e tile bf16, pitch 140
    __shared__ unsigned short sY[64 * 268];   // Y tile bf16, pitch 268

    const int blk  = blockIdx.x;              // 4096 blocks
    const int jq   = blk & 3;
    const int i    = (blk >> 2) & 255;
    const int b    = blk >> 10;
    const int j0   = jq * 64;
    const int tid  = threadIdx.x;
    const int wave = tid >> 6;                // 0..7
    const int lane = tid & 63;
    const int quad = lane >> 4;
    const int l16  = lane & 15;

    // ---- stage e tile [64 x 128] fp32 -> bf16 LDS (4 iters across 512 thr)
    {
        const float4* src4 = (const float4*)(e + (size_t)((b * NN + i) * NN + j0) * ED);
        #pragma unroll
        for (int it = 0; it < 4; ++it) {
            int idx4 = tid + it * 512;
            float4 v = src4[idx4];
            int elem = idx4 * 4, row = elem >> 7, col = elem & 127;
            short4 p = make_short4((short)f2bf(v.x), (short)f2bf(v.y),
                                   (short)f2bf(v.z), (short)f2bf(v.w));
            *(short4*)&sE[row * 140 + col] = p;
        }
    }

    const float* Qrow = Qs + (size_t)(b * NN + i) * XD;
    const float bo = beo[wave * 16 + l16];    // GEMM2 o-col bias

    __syncthreads();

    // ---- GEMM1 + combine: wave owns 32 c = 2 ct-slices, ct-outer
    #pragma unroll
    for (int ct = 0; ct < 2; ++ct) {
        const int c0 = wave * 32 + ct * 16;
        const int cc = c0 + l16;
        const float qsv = Qrow[cc];
        const float bmv = bem[cc] + 1.0f;
        const float bav = bea[cc];
        const int   ktA = (b * 256 + cc) * 256 + j0 + quad * 4;

        // register-resident B fragments for this ct (reused by all 4 m-chunks)
        short8 B1[4], B2[4];
        #pragma unroll
        for (int ks = 0; ks < 4; ++ks) {
            B1[ks] = *(const short8*)&WemT[cc * 128 + ks * 32 + quad * 8];
            B2[ks] = *(const short8*)&WeaT[cc * 128 + ks * 32 + quad * 8];
        }
        #pragma unroll
        for (int mc = 0; mc < 4; ++mc) {
            const int m0 = mc * 16;
            f32x4 kv = *(const f32x4*)&KT[ktA + m0];   // issue before MFMA
            f32x4 aE1 = {}, aE2 = {};
            __builtin_amdgcn_s_setprio(1);
            #pragma unroll
            for (int ks = 0; ks < 4; ++ks) {
                short8 a = *(const short8*)&sE[(m0 + l16) * 140 + ks * 32 + quad * 8];
                aE1 = MFMA16(a, B1[ks], aE1);
                aE2 = MFMA16(a, B2[ks], aE2);
            }
            __builtin_amdgcn_s_setprio(0);
            #pragma unroll
            for (int r = 0; r < 4; ++r) {
                float y = qsv * kv[r] * (aE1[r] + bmv) + (aE2[r] + bav);
                sY[(m0 + quad * 4 + r) * 268 + cc] = f2bf(y);
            }
        }
    }
    __syncthreads();

    // ---- GEMM2: newE[64 x 128] = Y @ Weo ; wave owns 16-col o-slice
    const int ow = wave * 16;
    short8 B3[8];
    #pragma unroll
    for (int ks = 0; ks < 8; ++ks)
        B3[ks] = *(const short8*)&WeoT[(ow + l16) * 256 + ks * 32 + quad * 8];
    f32x4 acc2[4] = {};
    __builtin_amdgcn_s_setprio(1);
    #pragma unroll
    for (int ks = 0; ks < 8; ++ks) {
        #pragma unroll
        for (int mt = 0; mt < 4; ++mt) {
            short8 a = *(const short8*)&sY[(mt * 16 + l16) * 268 + ks * 32 + quad * 8];
            acc2[mt] = MFMA16(a, B3[ks], acc2[mt]);
        }
    }
    __builtin_amdgcn_s_setprio(0);
    float* outBase = outE + (size_t)((b * NN + i) * NN + j0) * ED;
    #pragma unroll
    for (int mt = 0; mt < 4; ++mt)
        #pragma unroll
        for (int r = 0; r < 4; ++r)
            outBase[(size_t)(mt * 16 + quad * 4 + r) * ED + ow + l16] = acc2[mt][r] + bo;
}

extern "C" void kernel_launch(void* const* d_in, const int* in_sizes, int n_in,
                              void* d_out, int out_size, void* d_ws, size_t ws_size,
                              hipStream_t stream)
{
    const float* x   = (const float*)d_in[0];
    const float* e   = (const float*)d_in[1];
    const float* Wq  = (const float*)d_in[2];
    const float* bq  = (const float*)d_in[3];
    const float* Wk  = (const float*)d_in[4];
    const float* bk  = (const float*)d_in[5];
    const float* Wv  = (const float*)d_in[6];
    const float* bv  = (const float*)d_in[7];
    const float* Wem = (const float*)d_in[8];
    const float* bem = (const float*)d_in[9];
    const float* Wea = (const float*)d_in[10];
    const float* bea = (const float*)d_in[11];
    const float* Wxo = (const float*)d_in[12];
    const float* bxo = (const float*)d_in[13];
    const float* Weo = (const float*)d_in[14];
    const float* beo = (const float*)d_in[15];

    float* outX = (float*)d_out;                 // newX: 262144 f32
    float* outE = (float*)d_out + 262144;        // newE: 33554432 f32

    float* Qs   = (float*)d_ws;                  // [1024][256] f32 (scaled)
    float* KT   = Qs + 262144;                   // [4][256 c][256 j] f32
    short* WqT  = (short*)(KT + 262144);         // [256][256] bf16
    short* WkT  = WqT + 65536;
    short* WvT  = WkT + 65536;
    short* WxoT = WvT + 65536;
    short* WemT = WxoT + 65536;                  // [256][128] bf16
    short* WeaT = WemT + 32768;
    short* WeoT = WeaT + 32768;                  // [128][256] bf16

    hipLaunchKernelGGL(wprep_kernel, dim3(352), dim3(256), 0, stream,
                       Wq, Wk, Wv, Wxo, Wem, Wea, Weo,
                       WqT, WkT, WvT, WxoT, WemT, WeaT, WeoT);
    hipLaunchKernelGGL(proj_qk_kernel, dim3(32), dim3(512), 0, stream,
                       x, WqT, WkT, bq, bk, Qs, KT);
    hipLaunchKernelGGL(proj_vx_kernel, dim3(16), dim3(512), 0, stream,
                       x, WvT, bv, WxoT, bxo, outX);
    hipLaunchKernelGGL(fused_edge_kernel, dim3(4096), dim3(512), 0, stream,
                       e, Qs, KT, WemT, WeaT, WeoT, bem, bea, beo, outE);
}

// Round 7
// 375.419 us; speedup vs baseline: 1.0027x; 1.0027x over previous
//
#include <hip/hip_runtime.h>

#define NN 256
#define XD 256
#define ED 128

typedef __attribute__((ext_vector_type(8))) short short8;
typedef __attribute__((ext_vector_type(4))) float f32x4;

__device__ __forceinline__ unsigned short f2bf(float f) {
    unsigned u = __builtin_bit_cast(unsigned, f);
    u += 0x7FFF + ((u >> 16) & 1);
    return (unsigned short)(u >> 16);
}

#define MFMA16(a, b, c) __builtin_amdgcn_mfma_f32_16x16x32_bf16(a, b, c, 0, 0, 0)

// ---------------------------------------------------------------------------
// Weight prep: transpose + bf16-convert all 7 weights to [n][k] layout.
// ---------------------------------------------------------------------------
__global__ __launch_bounds__(256) void wprep_kernel(
    const float* __restrict__ Wq, const float* __restrict__ Wk,
    const float* __restrict__ Wv, const float* __restrict__ Wxo,
    const float* __restrict__ Wem, const float* __restrict__ Wea,
    const float* __restrict__ Weo,
    short* __restrict__ WqT, short* __restrict__ WkT,
    short* __restrict__ WvT, short* __restrict__ WxoT,
    short* __restrict__ WemT, short* __restrict__ WeaT,
    short* __restrict__ WeoT)
{
    __shared__ float sT[32][33];
    int blk = blockIdx.x;
    const float* src; short* dst; int din, dout, tile;
    if (blk < 256) {
        int m = blk >> 6; tile = blk & 63; din = 256; dout = 256;
        src = m == 0 ? Wq : (m == 1 ? Wk : (m == 2 ? Wv : Wxo));
        dst = m == 0 ? WqT : (m == 1 ? WkT : (m == 2 ? WvT : WxoT));
    } else if (blk < 320) {
        int m = (blk - 256) >> 5; tile = (blk - 256) & 31; din = 128; dout = 256;
        src = m == 0 ? Wem : Wea; dst = m == 0 ? WemT : WeaT;
    } else {
        tile = blk - 320; din = 256; dout = 128;
        src = Weo; dst = WeoT;
    }
    int ksh = (din == 256) ? 3 : 2;
    int kt = tile & ((1 << ksh) - 1);
    int nt = tile >> ksh;
    int c = threadIdx.x & 31, rbase = threadIdx.x >> 5;
    #pragma unroll
    for (int p = 0; p < 4; ++p) {
        int r = rbase + p * 8;
        sT[r][c] = src[(kt * 32 + r) * dout + nt * 32 + c];
    }
    __syncthreads();
    #pragma unroll
    for (int p = 0; p < 4; ++p) {
        int r = rbase + p * 8;
        dst[(nt * 32 + r) * din + kt * 32 + c] = (short)f2bf(sT[c][r]);
    }
}

// ---------------------------------------------------------------------------
// Q/K projection via MFMA. grid = 16 m-tiles (64 rows) x 2 mats = 32 blocks.
// Q row-major fp32 pre-scaled by 1/sqrt(32); K stored transposed KT[b][c][j].
// ---------------------------------------------------------------------------
__global__ __launch_bounds__(512) void proj_qk_kernel(
    const float* __restrict__ x, const short* __restrict__ WqT,
    const short* __restrict__ WkT, const float* __restrict__ bq,
    const float* __restrict__ bk, float* __restrict__ Qs,
    float* __restrict__ KT)
{
    __shared__ unsigned short sX[64 * 264];
    const int blk = blockIdx.x;
    const int mtile = blk >> 1;   // 0..15 (64-row tile of the 1024 rows)
    const int mat   = blk & 1;    // 0: Q, 1: K
    const int tid = threadIdx.x, wave = tid >> 6, lane = tid & 63;
    const int quad = lane >> 4, l16 = lane & 15;

    {   // stage x tile fp32 -> bf16
        const float4* src4 = (const float4*)(x + (size_t)mtile * 64 * XD);
        #pragma unroll
        for (int it = 0; it < 8; ++it) {
            int idx4 = tid + it * 512;
            float4 v = src4[idx4];
            int elem = idx4 * 4, row = elem >> 8, col = elem & 255;
            short4 p = make_short4((short)f2bf(v.x), (short)f2bf(v.y),
                                   (short)f2bf(v.z), (short)f2bf(v.w));
            *(short4*)&sX[row * 264 + col] = p;
        }
    }
    __syncthreads();

    const short* WT   = mat ? WkT : WqT;
    const float* bias = mat ? bk : bq;
    const int c0 = wave * 32;

    f32x4 acc[4][2] = {};
    for (int ks = 0; ks < 8; ++ks) {
        short8 bfrag[2];
        #pragma unroll
        for (int ct = 0; ct < 2; ++ct)
            bfrag[ct] = *(const short8*)&WT[(c0 + ct * 16 + l16) * 256 + ks * 32 + quad * 8];
        #pragma unroll
        for (int mt = 0; mt < 4; ++mt) {
            short8 a = *(const short8*)&sX[(mt * 16 + l16) * 264 + ks * 32 + quad * 8];
            acc[mt][0] = MFMA16(a, bfrag[0], acc[mt][0]);
            acc[mt][1] = MFMA16(a, bfrag[1], acc[mt][1]);
        }
    }

    if (mat == 0) {
        #pragma unroll
        for (int mt = 0; mt < 4; ++mt)
            #pragma unroll
            for (int ct = 0; ct < 2; ++ct) {
                int cc = c0 + ct * 16 + l16;
                float bb = bias[cc];
                #pragma unroll
                for (int r = 0; r < 4; ++r)
                    Qs[(size_t)(mtile * 64 + mt * 16 + quad * 4 + r) * 256 + cc] =
                        (acc[mt][ct][r] + bb) * 0.17677669529663687f;
            }
    } else {
        int b = mtile >> 2, j0p = (mtile & 3) * 64;
        #pragma unroll
        for (int mt = 0; mt < 4; ++mt)
            #pragma unroll
            for (int ct = 0; ct < 2; ++ct) {
                int cc = c0 + ct * 16 + l16;
                float bb = bias[cc];
                f32x4 st;
                #pragma unroll
                for (int r = 0; r < 4; ++r) st[r] = acc[mt][ct][r] + bb;
                *(f32x4*)&KT[(size_t)(b * 256 + cc) * 256 + j0p + mt * 16 + quad * 4] = st;
            }
    }
}

// ---------------------------------------------------------------------------
// V = x@Wv + bv (bf16 in LDS), then newX = V@Wxo + bxo.
// grid = 16 m-tiles (64 rows), 512 threads.
// ---------------------------------------------------------------------------
__global__ __launch_bounds__(512) void proj_vx_kernel(
    const float* __restrict__ x, const short* __restrict__ WvT,
    const float* __restrict__ bv, const short* __restrict__ WxoT,
    const float* __restrict__ bxo, float* __restrict__ outX)
{
    __shared__ unsigned short sX[64 * 264];
    __shared__ unsigned short sV[64 * 264];
    const int mtile = blockIdx.x;
    const int tid = threadIdx.x, wave = tid >> 6, lane = tid & 63;
    const int quad = lane >> 4, l16 = lane & 15;

    {
        const float4* src4 = (const float4*)(x + (size_t)mtile * 64 * XD);
        #pragma unroll
        for (int it = 0; it < 8; ++it) {
            int idx4 = tid + it * 512;
            float4 v = src4[idx4];
            int elem = idx4 * 4, row = elem >> 8, col = elem & 255;
            short4 p = make_short4((short)f2bf(v.x), (short)f2bf(v.y),
                                   (short)f2bf(v.z), (short)f2bf(v.w));
            *(short4*)&sX[row * 264 + col] = p;
        }
    }
    __syncthreads();

    const int c0 = wave * 32;
    f32x4 acc[4][2] = {};
    for (int ks = 0; ks < 8; ++ks) {
        short8 bfrag[2];
        #pragma unroll
        for (int ct = 0; ct < 2; ++ct)
            bfrag[ct] = *(const short8*)&WvT[(c0 + ct * 16 + l16) * 256 + ks * 32 + quad * 8];
        #pragma unroll
        for (int mt = 0; mt < 4; ++mt) {
            short8 a = *(const short8*)&sX[(mt * 16 + l16) * 264 + ks * 32 + quad * 8];
            acc[mt][0] = MFMA16(a, bfrag[0], acc[mt][0]);
            acc[mt][1] = MFMA16(a, bfrag[1], acc[mt][1]);
        }
    }
    #pragma unroll
    for (int mt = 0; mt < 4; ++mt)
        #pragma unroll
        for (int ct = 0; ct < 2; ++ct) {
            int cc = c0 + ct * 16 + l16;
            float bb = bv[cc];
            #pragma unroll
            for (int r = 0; r < 4; ++r)
                sV[(mt * 16 + quad * 4 + r) * 264 + cc] = f2bf(acc[mt][ct][r] + bb);
        }
    __syncthreads();

    f32x4 acc2[4][2] = {};
    for (int ks = 0; ks < 8; ++ks) {
        short8 bfrag[2];
        #pragma unroll
        for (int ct = 0; ct < 2; ++ct)
            bfrag[ct] = *(const short8*)&WxoT[(c0 + ct * 16 + l16) * 256 + ks * 32 + quad * 8];
        #pragma unroll
        for (int mt = 0; mt < 4; ++mt) {
            short8 a = *(const short8*)&sV[(mt * 16 + l16) * 264 + ks * 32 + quad * 8];
            acc2[mt][0] = MFMA16(a, bfrag[0], acc2[mt][0]);
            acc2[mt][1] = MFMA16(a, bfrag[1], acc2[mt][1]);
        }
    }
    #pragma unroll
    for (int mt = 0; mt < 4; ++mt)
        #pragma unroll
        for (int ct = 0; ct < 2; ++ct) {
            int cc = c0 + ct * 16 + l16;
            float bb = bxo[cc];
            #pragma unroll
            for (int r = 0; r < 4; ++r)
                outX[(size_t)(mtile * 64 + mt * 16 + quad * 4 + r) * 256 + cc] =
                    acc2[mt][ct][r] + bb;
        }
}

// ---------------------------------------------------------------------------
// Fused edge kernel v10 = v8 (best: 167.6us) + exposed-latency/L2-thrash fixes:
//  - e loads + outE stores NON-TEMPORAL (touched once; stop evicting the
//    reused KT/weights working set from the 4MB/XCD L2).
//  - kv (KT) loads batched: all 8 f32x4 of a c-pass issued before the mc-loop
//    (one exposed latency per pass instead of 8 per wave). +32 VGPR; LDS is
//    the occupancy limiter so VGPR<=170 is free at (256,3).
//  - B3 prefetched before the 2nd barrier (drained by barrier vmcnt(0) while
//    other blocks compute, not serially after).
//  - setprio kept (v8: +2.5%).
// ---------------------------------------------------------------------------
__global__ __launch_bounds__(256, 3) void fused_edge_kernel(
    const float* __restrict__ e, const float* __restrict__ Qs,
    const float* __restrict__ KT, const short* __restrict__ WemT,
    const short* __restrict__ WeaT, const short* __restrict__ WeoT,
    const float* __restrict__ bem, const float* __restrict__ bea,
    const float* __restrict__ beo, float* __restrict__ outE)
{
    __shared__ unsigned short sE[64 * 140];   // e tile bf16, pitch 140
    __shared__ unsigned short sY[64 * 268];   // Y tile bf16, pitch 268

    const int blk  = blockIdx.x;              // 4096 blocks
    const int jq   = blk & 3;
    const int i    = (blk >> 2) & 255;
    const int b    = blk >> 10;
    const int j0   = jq * 64;
    const int tid  = threadIdx.x;
    const int wave = tid >> 6;
    const int lane = tid & 63;
    const int quad = lane >> 4;
    const int l16  = lane & 15;

    // ---- stage e tile [64 x 128] fp32 -> bf16 LDS (non-temporal reads)
    {
        const f32x4* src4 = (const f32x4*)(e + (size_t)((b * NN + i) * NN + j0) * ED);
        #pragma unroll
        for (int it = 0; it < 8; ++it) {
            int idx4 = tid + it * 256;
            f32x4 v = __builtin_nontemporal_load(&src4[idx4]);
            int elem = idx4 * 4, row = elem >> 7, col = elem & 127;
            short4 p = make_short4((short)f2bf(v[0]), (short)f2bf(v[1]),
                                   (short)f2bf(v[2]), (short)f2bf(v[3]));
            *(short4*)&sE[row * 140 + col] = p;
        }
    }

    const float* Qrow = Qs + (size_t)(b * NN + i) * XD;
    float bo[2];
    #pragma unroll
    for (int ct = 0; ct < 2; ++ct) bo[ct] = beo[wave * 32 + ct * 16 + l16];

    __syncthreads();

    // ---- GEMM1 + combine, pass-outer over column halves
    #pragma unroll
    for (int p = 0; p < 2; ++p) {
        const int c0 = wave * 32 + p * 128;
        float qsv[2], bmv[2], bav[2];
        int ktA[2];
        #pragma unroll
        for (int ct = 0; ct < 2; ++ct) {
            int cc = c0 + ct * 16 + l16;
            qsv[ct] = Qrow[cc];
            bmv[ct] = bem[cc] + 1.0f;
            bav[ct] = bea[cc];
            ktA[ct] = (b * 256 + cc) * 256 + j0 + quad * 4;
        }
        // register-resident B fragments for this pass (reused by all 4 m-chunks)
        short8 B1[4][2], B2[4][2];
        #pragma unroll
        for (int ks = 0; ks < 4; ++ks)
            #pragma unroll
            for (int ct = 0; ct < 2; ++ct) {
                int n = c0 + ct * 16 + l16;
                B1[ks][ct] = *(const short8*)&WemT[n * 128 + ks * 32 + quad * 8];
                B2[ks][ct] = *(const short8*)&WeaT[n * 128 + ks * 32 + quad * 8];
            }
        // batched kv prefetch for this pass: one exposed latency, not 8
        f32x4 kvp[4][2];
        #pragma unroll
        for (int mc = 0; mc < 4; ++mc)
            #pragma unroll
            for (int ct = 0; ct < 2; ++ct)
                kvp[mc][ct] = *(const f32x4*)&KT[ktA[ct] + mc * 16];
        #pragma unroll
        for (int mc = 0; mc < 4; ++mc) {
            const int m0 = mc * 16;
            f32x4 aE1[2] = {}, aE2[2] = {};
            __builtin_amdgcn_s_setprio(1);
            #pragma unroll
            for (int ks = 0; ks < 4; ++ks) {
                short8 a = *(const short8*)&sE[(m0 + l16) * 140 + ks * 32 + quad * 8];
                aE1[0] = MFMA16(a, B1[ks][0], aE1[0]);
                aE1[1] = MFMA16(a, B1[ks][1], aE1[1]);
                aE2[0] = MFMA16(a, B2[ks][0], aE2[0]);
                aE2[1] = MFMA16(a, B2[ks][1], aE2[1]);
            }
            __builtin_amdgcn_s_setprio(0);
            #pragma unroll
            for (int ct = 0; ct < 2; ++ct) {
                int cc = c0 + ct * 16 + l16;
                #pragma unroll
                for (int r = 0; r < 4; ++r) {
                    float y = qsv[ct] * kvp[mc][ct][r] * (aE1[ct][r] + bmv[ct])
                              + (aE2[ct][r] + bav[ct]);
                    sY[(m0 + quad * 4 + r) * 268 + cc] = f2bf(y);
                }
            }
        }
    }

    // ---- GEMM2 B-frags prefetched BEFORE the barrier (drained by barrier)
    short8 B3[8][2];
    #pragma unroll
    for (int ks = 0; ks < 8; ++ks)
        #pragma unroll
        for (int ct = 0; ct < 2; ++ct)
            B3[ks][ct] = *(const short8*)&WeoT[(wave * 32 + ct * 16 + l16) * 256 + ks * 32 + quad * 8];
    __syncthreads();

    // ---- GEMM2: newE[64 x 128] = Y @ Weo ; wave owns 32-col n-slice
    f32x4 acc2[4][2] = {};
    __builtin_amdgcn_s_setprio(1);
    #pragma unroll
    for (int ks = 0; ks < 8; ++ks) {
        #pragma unroll
        for (int mt = 0; mt < 4; ++mt) {
            short8 a = *(const short8*)&sY[(mt * 16 + l16) * 268 + ks * 32 + quad * 8];
            acc2[mt][0] = MFMA16(a, B3[ks][0], acc2[mt][0]);
            acc2[mt][1] = MFMA16(a, B3[ks][1], acc2[mt][1]);
        }
    }
    __builtin_amdgcn_s_setprio(0);
    float* outBase = outE + (size_t)((b * NN + i) * NN + j0) * ED;
    #pragma unroll
    for (int mt = 0; mt < 4; ++mt)
        #pragma unroll
        for (int ct = 0; ct < 2; ++ct) {
            int col = wave * 32 + ct * 16 + l16;
            #pragma unroll
            for (int r = 0; r < 4; ++r)
                __builtin_nontemporal_store(acc2[mt][ct][r] + bo[ct],
                    &outBase[(size_t)(mt * 16 + quad * 4 + r) * ED + col]);
        }
}

extern "C" void kernel_launch(void* const* d_in, const int* in_sizes, int n_in,
                              void* d_out, int out_size, void* d_ws, size_t ws_size,
                              hipStream_t stream)
{
    const float* x   = (const float*)d_in[0];
    const float* e   = (const float*)d_in[1];
    const float* Wq  = (const float*)d_in[2];
    const float* bq  = (const float*)d_in[3];
    const float* Wk  = (const float*)d_in[4];
    const float* bk  = (const float*)d_in[5];
    const float* Wv  = (const float*)d_in[6];
    const float* bv  = (const float*)d_in[7];
    const float* Wem = (const float*)d_in[8];
    const float* bem = (const float*)d_in[9];
    const float* Wea = (const float*)d_in[10];
    const float* bea = (const float*)d_in[11];
    const float* Wxo = (const float*)d_in[12];
    const float* bxo = (const float*)d_in[13];
    const float* Weo = (const float*)d_in[14];
    const float* beo = (const float*)d_in[15];

    float* outX = (float*)d_out;                 // newX: 262144 f32
    float* outE = (float*)d_out + 262144;        // newE: 33554432 f32

    float* Qs   = (float*)d_ws;                  // [1024][256] f32 (scaled)
    float* KT   = Qs + 262144;                   // [4][256 c][256 j] f32
    short* WqT  = (short*)(KT + 262144);         // [256][256] bf16
    short* WkT  = WqT + 65536;
    short* WvT  = WkT + 65536;
    short* WxoT = WvT + 65536;
    short* WemT = WxoT + 65536;                  // [256][128] bf16
    short* WeaT = WemT + 32768;
    short* WeoT = WeaT + 32768;                  // [128][256] bf16

    hipLaunchKernelGGL(wprep_kernel, dim3(352), dim3(256), 0, stream,
                       Wq, Wk, Wv, Wxo, Wem, Wea, Weo,
                       WqT, WkT, WvT, WxoT, WemT, WeaT, WeoT);
    hipLaunchKernelGGL(proj_qk_kernel, dim3(32), dim3(512), 0, stream,
                       x, WqT, WkT, bq, bk, Qs, KT);
    hipLaunchKernelGGL(proj_vx_kernel, dim3(16), dim3(512), 0, stream,
                       x, WvT, bv, WxoT, bxo, outX);
    hipLaunchKernelGGL(fused_edge_kernel, dim3(4096), dim3(256), 0, stream,
                       e, Qs, KT, WemT, WeaT, WeoT, bem, bea, beo, outE);
}